// Round 5
// baseline (1105.672 us; speedup 1.0000x reference)
//
#include <hip/hip_runtime.h>
#include <math.h>

#define N_NODES 50000
#define N_EDGES 800000
#define IN_C    256
#define HID     96
#define OUT_C   64
#define NLAYER  3

// ---------------- CSR build ----------------
// NOTE: harness passes integer inputs as int32.

__global__ void k_init(int* cnt, int* cur, int* counter,
                       int* col, float* wgt, int n) {
    int v = blockIdx.x * blockDim.x + threadIdx.x;
    if (v < n) { cnt[v] = 0; cur[v] = 0; }
    if (v == 0) *counter = 0;
    if (v < 8) { col[N_EDGES + v] = 0; wgt[N_EDGES + v] = 0.f; }  // pad for unroll-8 overread
}

__global__ void k_count(const int* __restrict__ ei, int* cnt, int e) {
    int i = blockIdx.x * blockDim.x + threadIdx.x;
    if (i < e) atomicAdd(&cnt[ei[e + i]], 1);   // row 1 = dst
}

__global__ void k_node(const int* __restrict__ cnt, float* __restrict__ dis,
                       int* __restrict__ start, int* counter, int n) {
    int v = blockIdx.x * blockDim.x + threadIdx.x;
    if (v < n) {
        int c = cnt[v];
        dis[v] = (float)(1.0 / sqrt((double)(c + 1)));  // deg incl self-loop >= 1
        start[v] = atomicAdd(counter, c);
    }
}

__global__ void k_fill(const int* __restrict__ ei, const float* __restrict__ dis,
                       const int* __restrict__ start, int* __restrict__ cur,
                       int* __restrict__ col, float* __restrict__ wgt, int e) {
    int i = blockIdx.x * blockDim.x + threadIdx.x;
    if (i < e) {
        int s = ei[i];
        int d = ei[e + i];
        int slot = start[d] + atomicAdd(&cur[d], 1);
        col[slot] = s;
        wgt[slot] = dis[s] * dis[d];
    }
}

// ---------------- dense GEMM: C[N x NOUT] = A[N x KTOT] @ W + bias -----------
// og = t % (NOUT/4): 4 outputs; ng = t / OG: 8 nodes.  x loads are 24-lane
// (OG-lane) broadcasts straight from global/L1 -- NO LDS staging for x, and
// no K-loop barriers.  Only W is staged in LDS (once per K-chunk).
// A cols [0,K1) come from A1 (row stride LDA1), cols [K1,KTOT) from A2
// (row stride HID) -- implements the concat for k_out.
// WRITEQ: also emit Cq = dithered-quantize(C).

template<int KTOT, int KC, int NOUT, int K1, int LDA1, bool BIAS, bool WRITEQ>
__global__ __launch_bounds__(192) void k_gemm(
    const float* __restrict__ A1, const float* __restrict__ A2,
    const float* __restrict__ W, const float* __restrict__ bias,
    const float* __restrict__ bn, float delta, float inv_delta,
    float* __restrict__ C, float* __restrict__ Cq)
{
    constexpr int OG    = NOUT / 4;       // 24 (NOUT=96) or 16 (NOUT=64)
    constexpr int NG    = 192 / OG;       // 8 or 12
    constexpr int NODES = NG * 8;         // 64 or 96
    __shared__ float Ws[KC * NOUT];

    const int t  = threadIdx.x;
    const int og = t % OG;
    const int ng = t / OG;
    const int n0 = blockIdx.x * NODES + ng * 8;

    float acc[8][4];
    #pragma unroll
    for (int r = 0; r < 8; r++)
        #pragma unroll
        for (int o = 0; o < 4; o++) acc[r][o] = 0.f;

    #pragma unroll
    for (int ch = 0; ch < KTOT / KC; ch++) {
        const int kc0 = ch * KC;
        __syncthreads();                   // protect Ws from previous chunk's readers
        for (int i = t * 4; i < KC * NOUT; i += 192 * 4)
            *(float4*)&Ws[i] = *(const float4*)&W[kc0 * NOUT + i];
        __syncthreads();

        // A source + per-node row pointers (tail rows clamped; stores guarded)
        const float* ap[8];
        #pragma unroll
        for (int r = 0; r < 8; r++) {
            int gn = n0 + r;
            if (gn > N_NODES - 1) gn = N_NODES - 1;
            if (kc0 < K1) ap[r] = A1 + (size_t)gn * LDA1 + kc0;
            else          ap[r] = A2 + (size_t)gn * HID  + (kc0 - K1);
        }

        #pragma unroll 2
        for (int k = 0; k < KC; k += 4) {
            float4 xv[8];
            #pragma unroll
            for (int r = 0; r < 8; r++) xv[r] = *(const float4*)(ap[r] + k);
            float4 w0 = *(const float4*)&Ws[(k + 0) * NOUT + 4 * og];
            float4 w1 = *(const float4*)&Ws[(k + 1) * NOUT + 4 * og];
            float4 w2 = *(const float4*)&Ws[(k + 2) * NOUT + 4 * og];
            float4 w3 = *(const float4*)&Ws[(k + 3) * NOUT + 4 * og];
            #pragma unroll
            for (int r = 0; r < 8; r++) {
                acc[r][0] = fmaf(xv[r].x, w0.x, acc[r][0]);
                acc[r][1] = fmaf(xv[r].x, w0.y, acc[r][1]);
                acc[r][2] = fmaf(xv[r].x, w0.z, acc[r][2]);
                acc[r][3] = fmaf(xv[r].x, w0.w, acc[r][3]);
                acc[r][0] = fmaf(xv[r].y, w1.x, acc[r][0]);
                acc[r][1] = fmaf(xv[r].y, w1.y, acc[r][1]);
                acc[r][2] = fmaf(xv[r].y, w1.z, acc[r][2]);
                acc[r][3] = fmaf(xv[r].y, w1.w, acc[r][3]);
                acc[r][0] = fmaf(xv[r].z, w2.x, acc[r][0]);
                acc[r][1] = fmaf(xv[r].z, w2.y, acc[r][1]);
                acc[r][2] = fmaf(xv[r].z, w2.z, acc[r][2]);
                acc[r][3] = fmaf(xv[r].z, w2.w, acc[r][3]);
                acc[r][0] = fmaf(xv[r].w, w3.x, acc[r][0]);
                acc[r][1] = fmaf(xv[r].w, w3.y, acc[r][1]);
                acc[r][2] = fmaf(xv[r].w, w3.z, acc[r][2]);
                acc[r][3] = fmaf(xv[r].w, w3.w, acc[r][3]);
            }
        }
    }

    // epilogue
    float4 bv = make_float4(0.f, 0.f, 0.f, 0.f);
    if (BIAS) bv = *(const float4*)&bias[4 * og];
    #pragma unroll
    for (int r = 0; r < 8; r++) {
        int gn = n0 + r;
        if (gn < N_NODES) {
            float4 c;
            c.x = acc[r][0] + bv.x;
            c.y = acc[r][1] + bv.y;
            c.z = acc[r][2] + bv.z;
            c.w = acc[r][3] + bv.w;
            *(float4*)&C[(size_t)gn * NOUT + 4 * og] = c;
            if (WRITEQ) {
                float4 b = *(const float4*)&bn[(size_t)gn * NOUT + 4 * og];
                float bx = b.x * delta, by = b.y * delta;
                float bz = b.z * delta, bw = b.w * delta;
                float4 q;
                q.x = floorf((c.x + bx) * inv_delta) * delta - bx;
                q.y = floorf((c.y + by) * inv_delta) * delta - by;
                q.z = floorf((c.z + bz) * inv_delta) * delta - bz;
                q.w = floorf((c.w + bw) * inv_delta) * delta - bw;
                *(float4*)&Cq[(size_t)gn * NOUT + 4 * og] = q;
            }
        }
    }
}

// ---------------- h = relu(segment_sum(m) + cb + eps), optionally quantized ---
// XCD-sliced gather: blockIdx&7 selects a 12-float column slice; each XCD's
// blocks gather only from a 2.4 MB slice of m -> per-XCD-L2 resident.
// Lanes: q = t%3 (float4 within slice), dl = t/3 (128 dsts/block).
// QUANT: writes hq for the NEXT layer (bn/delta of layer k+1).

template<bool QUANT>
__global__ __launch_bounds__(384) void k_agg(
    const float* __restrict__ m, const int* __restrict__ col,
    const float* __restrict__ wgt, const int* __restrict__ start,
    const int* __restrict__ cnt, const float* __restrict__ dis,
    const float* __restrict__ cb, const float* __restrict__ eps,
    const float* __restrict__ bn, float delta, float inv_delta,
    float* __restrict__ hout)
{
    const int slice  = blockIdx.x & 7;
    const int dchunk = blockIdx.x >> 3;
    const int t  = threadIdx.x;
    const int q  = t % 3;
    const int dl = t / 3;
    const int d  = dchunk * 128 + dl;
    if (d >= N_NODES) return;
    const int off = slice * 12 + q * 4;
    const int s0 = start[d], c = cnt[d];
    const float* mo = m + off;

    float4 a0 = {0,0,0,0}, a1 = {0,0,0,0}, a2 = {0,0,0,0}, a3 = {0,0,0,0};
    float4 a4 = {0,0,0,0}, a5 = {0,0,0,0}, a6 = {0,0,0,0}, a7 = {0,0,0,0};
    for (int e = 0; e < c; e += 8) {
        int i0 = col[s0 + e + 0]; float w0 = (e + 0 < c) ? wgt[s0 + e + 0] : 0.f;
        int i1 = col[s0 + e + 1]; float w1 = (e + 1 < c) ? wgt[s0 + e + 1] : 0.f;
        int i2 = col[s0 + e + 2]; float w2 = (e + 2 < c) ? wgt[s0 + e + 2] : 0.f;
        int i3 = col[s0 + e + 3]; float w3 = (e + 3 < c) ? wgt[s0 + e + 3] : 0.f;
        int i4 = col[s0 + e + 4]; float w4 = (e + 4 < c) ? wgt[s0 + e + 4] : 0.f;
        int i5 = col[s0 + e + 5]; float w5 = (e + 5 < c) ? wgt[s0 + e + 5] : 0.f;
        int i6 = col[s0 + e + 6]; float w6 = (e + 6 < c) ? wgt[s0 + e + 6] : 0.f;
        int i7 = col[s0 + e + 7]; float w7 = (e + 7 < c) ? wgt[s0 + e + 7] : 0.f;
        float4 v0 = *(const float4*)(mo + (size_t)i0 * HID);
        float4 v1 = *(const float4*)(mo + (size_t)i1 * HID);
        float4 v2 = *(const float4*)(mo + (size_t)i2 * HID);
        float4 v3 = *(const float4*)(mo + (size_t)i3 * HID);
        float4 v4 = *(const float4*)(mo + (size_t)i4 * HID);
        float4 v5 = *(const float4*)(mo + (size_t)i5 * HID);
        float4 v6 = *(const float4*)(mo + (size_t)i6 * HID);
        float4 v7 = *(const float4*)(mo + (size_t)i7 * HID);
        a0.x = fmaf(v0.x, w0, a0.x); a0.y = fmaf(v0.y, w0, a0.y);
        a0.z = fmaf(v0.z, w0, a0.z); a0.w = fmaf(v0.w, w0, a0.w);
        a1.x = fmaf(v1.x, w1, a1.x); a1.y = fmaf(v1.y, w1, a1.y);
        a1.z = fmaf(v1.z, w1, a1.z); a1.w = fmaf(v1.w, w1, a1.w);
        a2.x = fmaf(v2.x, w2, a2.x); a2.y = fmaf(v2.y, w2, a2.y);
        a2.z = fmaf(v2.z, w2, a2.z); a2.w = fmaf(v2.w, w2, a2.w);
        a3.x = fmaf(v3.x, w3, a3.x); a3.y = fmaf(v3.y, w3, a3.y);
        a3.z = fmaf(v3.z, w3, a3.z); a3.w = fmaf(v3.w, w3, a3.w);
        a4.x = fmaf(v4.x, w4, a4.x); a4.y = fmaf(v4.y, w4, a4.y);
        a4.z = fmaf(v4.z, w4, a4.z); a4.w = fmaf(v4.w, w4, a4.w);
        a5.x = fmaf(v5.x, w5, a5.x); a5.y = fmaf(v5.y, w5, a5.y);
        a5.z = fmaf(v5.z, w5, a5.z); a5.w = fmaf(v5.w, w5, a5.w);
        a6.x = fmaf(v6.x, w6, a6.x); a6.y = fmaf(v6.y, w6, a6.y);
        a6.z = fmaf(v6.z, w6, a6.z); a6.w = fmaf(v6.w, w6, a6.w);
        a7.x = fmaf(v7.x, w7, a7.x); a7.y = fmaf(v7.y, w7, a7.y);
        a7.z = fmaf(v7.z, w7, a7.z); a7.w = fmaf(v7.w, w7, a7.w);
    }
    float4 a;
    a.x = ((a0.x + a1.x) + (a2.x + a3.x)) + ((a4.x + a5.x) + (a6.x + a7.x));
    a.y = ((a0.y + a1.y) + (a2.y + a3.y)) + ((a4.y + a5.y) + (a6.y + a7.y));
    a.z = ((a0.z + a1.z) + (a2.z + a3.z)) + ((a4.z + a5.z) + (a6.z + a7.z));
    a.w = ((a0.w + a1.w) + (a2.w + a3.w)) + ((a4.w + a5.w) + (a6.w + a7.w));
    float dv = dis[d];
    float sw = dv * dv;
    float4 sv = *(const float4*)(mo + (size_t)d * HID);   // self-loop
    a.x = fmaf(sv.x, sw, a.x); a.y = fmaf(sv.y, sw, a.y);
    a.z = fmaf(sv.z, sw, a.z); a.w = fmaf(sv.w, sw, a.w);
    float4 cbv = *(const float4*)&cb[off];
    float4 ev  = *(const float4*)&eps[(size_t)d * HID + off];
    float hx = fmaxf(a.x + cbv.x + ev.x, 0.f);
    float hy = fmaxf(a.y + cbv.y + ev.y, 0.f);
    float hz = fmaxf(a.z + cbv.z + ev.z, 0.f);
    float hw = fmaxf(a.w + cbv.w + ev.w, 0.f);
    float4 o;
    if (QUANT) {
        float4 b = *(const float4*)&bn[(size_t)d * HID + off];
        float bx = b.x * delta, by = b.y * delta;
        float bz = b.z * delta, bw = b.w * delta;
        o.x = floorf((hx + bx) * inv_delta) * delta - bx;
        o.y = floorf((hy + by) * inv_delta) * delta - by;
        o.z = floorf((hz + bz) * inv_delta) * delta - bz;
        o.w = floorf((hw + bw) * inv_delta) * delta - bw;
    } else {
        o.x = hx; o.y = hy; o.z = hz; o.w = hw;
    }
    *(float4*)&hout[(size_t)d * HID + off] = o;
}

// ---------------- launch ----------------

extern "C" void kernel_launch(void* const* d_in, const int* in_sizes, int n_in,
                              void* d_out, int out_size, void* d_ws, size_t ws_size,
                              hipStream_t stream) {
    (void)in_sizes; (void)n_in; (void)out_size; (void)ws_size;
    const float* x       = (const float*)d_in[0];
    const int*   ei      = (const int*)d_in[1];     // int32 per harness convention
    const float* proj_w  = (const float*)d_in[2];
    const float* proj_b  = (const float*)d_in[3];
    const float* conv_w  = (const float*)d_in[4];
    const float* conv_b  = (const float*)d_in[5];
    const float* out_w   = (const float*)d_in[6];
    const float* out_b   = (const float*)d_in[7];
    const float* b_noise = (const float*)d_in[8];
    const float* eps_n   = (const float*)d_in[9];
    float*       out     = (float*)d_out;

    char* w = (char*)d_ws;
    size_t off = 0;
    auto alloc = [&](size_t bytes) -> char* {
        char* p = w + off;
        off = (off + bytes + 255) & ~(size_t)255;
        return p;
    };
    float* h0b   = (float*)alloc((size_t)N_NODES * HID * 4);
    float* hq    = (float*)alloc((size_t)N_NODES * HID * 4);  // quantized h (in place across layers; final h for k_out)
    float* mb    = (float*)alloc((size_t)N_NODES * HID * 4);
    float* dis   = (float*)alloc((size_t)N_NODES * 4);
    float* wgt   = (float*)alloc((size_t)(N_EDGES + 8) * 4);
    int*   col   = (int*)  alloc((size_t)(N_EDGES + 8) * 4);
    int*   cnt   = (int*)  alloc((size_t)N_NODES * 4);
    int*   cur   = (int*)  alloc((size_t)N_NODES * 4);
    int*   start = (int*)  alloc((size_t)N_NODES * 4);
    int*   ctr   = (int*)  alloc(256);

    // CSR build
    k_init <<<(N_NODES + 255) / 256, 256, 0, stream>>>(cnt, cur, ctr, col, wgt, N_NODES);
    k_count<<<(N_EDGES + 255) / 256, 256, 0, stream>>>(ei, cnt, N_EDGES);
    k_node <<<(N_NODES + 255) / 256, 256, 0, stream>>>(cnt, dis, start, ctr, N_NODES);
    k_fill <<<(N_EDGES + 255) / 256, 256, 0, stream>>>(ei, dis, start, cur, col, wgt, N_EDGES);

    const float deltas[NLAYER] = {1.0f, 0.5f, 0.25f};
    const int g96  = (N_NODES + 63) / 64;   // 782  (NOUT=96: 64 nodes/block)
    const int g64  = (N_NODES + 95) / 96;   // 521  (NOUT=64: 96 nodes/block)
    const int gagg = 8 * ((N_NODES + 127) / 128);   // 3128

    // h0 = x @ proj_w + proj_b; also hq0 = quantize(h0, bn[0], delta0)
    k_gemm<256, 128, HID, 256, IN_C, true, true><<<g96, 192, 0, stream>>>(
        x, nullptr, proj_w, proj_b,
        b_noise, deltas[0], 1.0f / deltas[0], h0b, hq);

    for (int k = 0; k < NLAYER; k++) {
        // m = hq @ conv_w[k]   (single K-chunk, W staged once, no K barriers)
        k_gemm<96, 96, HID, 96, HID, false, false><<<g96, 192, 0, stream>>>(
            hq, nullptr, conv_w + (size_t)k * HID * HID, nullptr,
            nullptr, 0.f, 0.f, mb, nullptr);
        // h = relu(agg + cb + eps); layers 0,1 write hq for next layer, layer 2 plain h
        if (k < NLAYER - 1) {
            k_agg<true><<<gagg, 384, 0, stream>>>(
                mb, col, wgt, start, cnt, dis,
                conv_b + (size_t)k * HID, eps_n + (size_t)k * N_NODES * HID,
                b_noise + (size_t)(k + 1) * N_NODES * HID,
                deltas[k + 1], 1.0f / deltas[k + 1], hq);
        } else {
            k_agg<false><<<gagg, 384, 0, stream>>>(
                mb, col, wgt, start, cnt, dis,
                conv_b + (size_t)k * HID, eps_n + (size_t)k * N_NODES * HID,
                nullptr, 0.f, 0.f, hq);
        }
    }

    // out = concat(h0, h) @ out_w + out_b  (chunk0 from h0b, chunk1 from hq)
    k_gemm<192, 96, OUT_C, 96, HID, true, false><<<g64, 192, 0, stream>>>(
        h0b, hq, out_w, out_b,
        nullptr, 0.f, 0.f, out, nullptr);
}

// Round 6
// 917.783 us; speedup vs baseline: 1.2047x; 1.2047x over previous
//
#include <hip/hip_runtime.h>
#include <math.h>

#define N_NODES 50000
#define N_EDGES 800000
#define IN_C    256
#define HID     96
#define OUT_C   64
#define NLAYER  3

// ---------------- CSR build ----------------
// NOTE: harness passes integer inputs as int32.

__global__ void k_init(int* cnt, int* cur, int* counter,
                       int* col, float* wgt, int n) {
    int v = blockIdx.x * blockDim.x + threadIdx.x;
    if (v < n) { cnt[v] = 0; cur[v] = 0; }
    if (v == 0) *counter = 0;
    if (v < 8) { col[N_EDGES + v] = 0; wgt[N_EDGES + v] = 0.f; }  // pad for unroll-8 overread
}

__global__ void k_count(const int* __restrict__ ei, int* cnt, int e) {
    int i = blockIdx.x * blockDim.x + threadIdx.x;
    if (i < e) atomicAdd(&cnt[ei[e + i]], 1);   // row 1 = dst
}

__global__ void k_node(const int* __restrict__ cnt, float* __restrict__ dis,
                       int* __restrict__ start, int* counter, int n) {
    int v = blockIdx.x * blockDim.x + threadIdx.x;
    if (v < n) {
        int c = cnt[v];
        dis[v] = (float)(1.0 / sqrt((double)(c + 1)));  // deg incl self-loop >= 1
        start[v] = atomicAdd(counter, c);
    }
}

__global__ void k_fill(const int* __restrict__ ei, const float* __restrict__ dis,
                       const int* __restrict__ start, int* __restrict__ cur,
                       int* __restrict__ col, float* __restrict__ wgt, int e) {
    int i = blockIdx.x * blockDim.x + threadIdx.x;
    if (i < e) {
        int s = ei[i];
        int d = ei[e + i];
        int slot = start[d] + atomicAdd(&cur[d], 1);
        col[slot] = s;
        wgt[slot] = dis[s] * dis[d];
    }
}

// ---------------- dense GEMM: C[N x NOUTS] = A[N x K] @ W + bias -------------
// Only the A-tile goes to LDS (coalesced float4 stage, row stride K+1 so the
// 64-distinct-row ds_read_b32 in the K loop is conflict-free 2-way).
// thread = (node = t % NODES, och = t / NODES); each thread computes OW
// consecutive outputs for one node. W operands are wave-uniform loads
// (scalar-load path, L1-hot) -- no W in LDS, no barriers in the K loop.
// A cols [0,K1) from A1 (row stride LDA1), [K1,K) from A2 (row stride HID).
// WRITEQ: also emit Cq = dithered-quantize(C).

template<int K, int NODES, int THREADS, int NOUTS, int K1, int LDA1,
         bool BIAS, bool WRITEQ>
__global__ __launch_bounds__(THREADS) void k_gemm(
    const float* __restrict__ A1, const float* __restrict__ A2,
    const float* __restrict__ W, const float* __restrict__ bias,
    const float* __restrict__ bn, float delta, float inv_delta,
    float* __restrict__ C, float* __restrict__ Cq)
{
    constexpr int NOCH = THREADS / NODES;
    constexpr int OW   = NOUTS / NOCH;
    constexpr int STR  = K + 1;
    __shared__ float xs[NODES * STR];

    const int t    = threadIdx.x;
    const int base = blockIdx.x * NODES;

    // stage A-tile: coalesced float4 reads, scalar LDS writes (stride K+1)
    constexpr int NF4 = NODES * (K / 4);
    for (int i = t; i < NF4; i += THREADS) {
        int node = i / (K / 4);
        int kc   = 4 * (i % (K / 4));
        int gn   = base + node;
        if (gn > N_NODES - 1) gn = N_NODES - 1;
        const float* src = (kc < K1)
            ? (A1 + (size_t)gn * LDA1 + kc)
            : (A2 + (size_t)gn * HID + (kc - K1));
        float4 v = *(const float4*)src;
        float* dst = &xs[node * STR + kc];
        dst[0] = v.x; dst[1] = v.y; dst[2] = v.z; dst[3] = v.w;
    }
    __syncthreads();

    const int node = t % NODES;
    const int och  = t / NODES;
    const int o0   = och * OW;
    const float* xrow = &xs[node * STR];
    const float* Wp   = W + o0;

    float acc[OW];
    #pragma unroll
    for (int o = 0; o < OW; o++) acc[o] = 0.f;

    #pragma unroll 4
    for (int k = 0; k < K; k++) {
        float a = xrow[k];                       // ds_read_b32, 2-way (free)
        const float* wr = Wp + (size_t)k * NOUTS; // wave-uniform -> scalar path
        #pragma unroll
        for (int o = 0; o < OW; o++) acc[o] = fmaf(a, wr[o], acc[o]);
    }

    int gn = base + node;
    if (gn < N_NODES) {
        #pragma unroll
        for (int o = 0; o < OW; o += 4) {
            float4 c;
            c.x = acc[o + 0] + (BIAS ? bias[o0 + o + 0] : 0.f);
            c.y = acc[o + 1] + (BIAS ? bias[o0 + o + 1] : 0.f);
            c.z = acc[o + 2] + (BIAS ? bias[o0 + o + 2] : 0.f);
            c.w = acc[o + 3] + (BIAS ? bias[o0 + o + 3] : 0.f);
            *(float4*)&C[(size_t)gn * NOUTS + o0 + o] = c;
            if (WRITEQ) {
                float4 b = *(const float4*)&bn[(size_t)gn * NOUTS + o0 + o];
                float bx = b.x * delta, by = b.y * delta;
                float bz = b.z * delta, bw = b.w * delta;
                float4 q;
                q.x = floorf((c.x + bx) * inv_delta) * delta - bx;
                q.y = floorf((c.y + by) * inv_delta) * delta - by;
                q.z = floorf((c.z + bz) * inv_delta) * delta - bz;
                q.w = floorf((c.w + bw) * inv_delta) * delta - bw;
                *(float4*)&Cq[(size_t)gn * NOUTS + o0 + o] = q;
            }
        }
    }
}

// ---------------- h = relu(segment_sum(m) + cb + eps), optionally quantized ---
// R3's measured-fast structure: one lane per feature (96), 4 dsts/block,
// unroll-8 independent gathers. QUANT writes hq for the NEXT layer.

template<bool QUANT>
__global__ __launch_bounds__(384) void k_agg(
    const float* __restrict__ m, const int* __restrict__ col,
    const float* __restrict__ wgt, const int* __restrict__ start,
    const int* __restrict__ cnt, const float* __restrict__ dis,
    const float* __restrict__ cb, const float* __restrict__ eps,
    const float* __restrict__ bn, float delta, float inv_delta,
    float* __restrict__ hout)
{
    const int tx = threadIdx.x;
    const int d  = blockIdx.x * 4 + threadIdx.y;   // 12500*4 == N_NODES
    const int s0 = start[d], c = cnt[d];
    const float* mt = m + tx;
    float a0 = 0.f, a1 = 0.f, a2 = 0.f, a3 = 0.f;
    float a4 = 0.f, a5 = 0.f, a6 = 0.f, a7 = 0.f;
    for (int e = 0; e < c; e += 8) {
        int i0 = col[s0 + e + 0]; float w0 = (e + 0 < c) ? wgt[s0 + e + 0] : 0.f;
        int i1 = col[s0 + e + 1]; float w1 = (e + 1 < c) ? wgt[s0 + e + 1] : 0.f;
        int i2 = col[s0 + e + 2]; float w2 = (e + 2 < c) ? wgt[s0 + e + 2] : 0.f;
        int i3 = col[s0 + e + 3]; float w3 = (e + 3 < c) ? wgt[s0 + e + 3] : 0.f;
        int i4 = col[s0 + e + 4]; float w4 = (e + 4 < c) ? wgt[s0 + e + 4] : 0.f;
        int i5 = col[s0 + e + 5]; float w5 = (e + 5 < c) ? wgt[s0 + e + 5] : 0.f;
        int i6 = col[s0 + e + 6]; float w6 = (e + 6 < c) ? wgt[s0 + e + 6] : 0.f;
        int i7 = col[s0 + e + 7]; float w7 = (e + 7 < c) ? wgt[s0 + e + 7] : 0.f;
        a0 = fmaf(mt[(size_t)i0 * HID], w0, a0);
        a1 = fmaf(mt[(size_t)i1 * HID], w1, a1);
        a2 = fmaf(mt[(size_t)i2 * HID], w2, a2);
        a3 = fmaf(mt[(size_t)i3 * HID], w3, a3);
        a4 = fmaf(mt[(size_t)i4 * HID], w4, a4);
        a5 = fmaf(mt[(size_t)i5 * HID], w5, a5);
        a6 = fmaf(mt[(size_t)i6 * HID], w6, a6);
        a7 = fmaf(mt[(size_t)i7 * HID], w7, a7);
    }
    float dv = dis[d];
    float a = ((a0 + a1) + (a2 + a3)) + ((a4 + a5) + (a6 + a7));
    a = fmaf(mt[(size_t)d * HID], dv * dv, a);     // self-loop
    a += cb[tx] + eps[(size_t)d * HID + tx];
    float h = fmaxf(a, 0.f);
    float o;
    if (QUANT) {
        float b = bn[(size_t)d * HID + tx] * delta;   // exact (delta = 2^-k)
        o = floorf((h + b) * inv_delta) * delta - b;
    } else {
        o = h;
    }
    hout[(size_t)d * HID + tx] = o;
}

// ---------------- launch ----------------

extern "C" void kernel_launch(void* const* d_in, const int* in_sizes, int n_in,
                              void* d_out, int out_size, void* d_ws, size_t ws_size,
                              hipStream_t stream) {
    (void)in_sizes; (void)n_in; (void)out_size; (void)ws_size;
    const float* x       = (const float*)d_in[0];
    const int*   ei      = (const int*)d_in[1];     // int32 per harness convention
    const float* proj_w  = (const float*)d_in[2];
    const float* proj_b  = (const float*)d_in[3];
    const float* conv_w  = (const float*)d_in[4];
    const float* conv_b  = (const float*)d_in[5];
    const float* out_w   = (const float*)d_in[6];
    const float* out_b   = (const float*)d_in[7];
    const float* b_noise = (const float*)d_in[8];
    const float* eps_n   = (const float*)d_in[9];
    float*       out     = (float*)d_out;

    char* w = (char*)d_ws;
    size_t off = 0;
    auto alloc = [&](size_t bytes) -> char* {
        char* p = w + off;
        off = (off + bytes + 255) & ~(size_t)255;
        return p;
    };
    float* h0b   = (float*)alloc((size_t)N_NODES * HID * 4);
    float* hq    = (float*)alloc((size_t)N_NODES * HID * 4);  // quantized h (in place; final h for k_out)
    float* mb    = (float*)alloc((size_t)N_NODES * HID * 4);
    float* dis   = (float*)alloc((size_t)N_NODES * 4);
    float* wgt   = (float*)alloc((size_t)(N_EDGES + 8) * 4);
    int*   col   = (int*)  alloc((size_t)(N_EDGES + 8) * 4);
    int*   cnt   = (int*)  alloc((size_t)N_NODES * 4);
    int*   cur   = (int*)  alloc((size_t)N_NODES * 4);
    int*   start = (int*)  alloc((size_t)N_NODES * 4);
    int*   ctr   = (int*)  alloc(256);

    // CSR build
    k_init <<<(N_NODES + 255) / 256, 256, 0, stream>>>(cnt, cur, ctr, col, wgt, N_NODES);
    k_count<<<(N_EDGES + 255) / 256, 256, 0, stream>>>(ei, cnt, N_EDGES);
    k_node <<<(N_NODES + 255) / 256, 256, 0, stream>>>(cnt, dis, start, ctr, N_NODES);
    k_fill <<<(N_EDGES + 255) / 256, 256, 0, stream>>>(ei, dis, start, cur, col, wgt, N_EDGES);

    const float deltas[NLAYER] = {1.0f, 0.5f, 0.25f};
    const int g64 = (N_NODES + 63) / 64;    // 782  (conv: 64-node tiles)
    const int g32 = (N_NODES + 31) / 32;    // 1563 (h0/out: 32-node tiles)

    // h0 = x @ proj_w + proj_b; also hq0 = quantize(h0, bn[0], delta0)
    // K=256, 32 nodes, 256 thr (8 och x 12 outs), LDS 32.9 KB
    k_gemm<256, 32, 256, HID, 256, IN_C, true, true><<<g32, 256, 0, stream>>>(
        x, nullptr, proj_w, proj_b,
        b_noise, deltas[0], 1.0f / deltas[0], h0b, hq);

    for (int k = 0; k < NLAYER; k++) {
        // m = hq @ conv_w[k]   (K=96, 64 nodes, 256 thr (4 och x 24), LDS 24.8 KB)
        k_gemm<96, 64, 256, HID, 96, HID, false, false><<<g64, 256, 0, stream>>>(
            hq, nullptr, conv_w + (size_t)k * HID * HID, nullptr,
            nullptr, 0.f, 0.f, mb, nullptr);
        // h = relu(agg + cb + eps); layers 0,1 write hq for next layer, layer 2 plain h
        if (k < NLAYER - 1) {
            k_agg<true><<<N_NODES / 4, dim3(96, 4), 0, stream>>>(
                mb, col, wgt, start, cnt, dis,
                conv_b + (size_t)k * HID, eps_n + (size_t)k * N_NODES * HID,
                b_noise + (size_t)(k + 1) * N_NODES * HID,
                deltas[k + 1], 1.0f / deltas[k + 1], hq);
        } else {
            k_agg<false><<<N_NODES / 4, dim3(96, 4), 0, stream>>>(
                mb, col, wgt, start, cnt, dis,
                conv_b + (size_t)k * HID, eps_n + (size_t)k * N_NODES * HID,
                nullptr, 0.f, 0.f, hq);
        }
    }

    // out = concat(h0, h) @ out_w + out_b  (K=192: cols [0,96) h0b, [96,192) hq)
    // 32 nodes, 256 thr (8 och x 8 outs), LDS 24.7 KB
    k_gemm<192, 32, 256, OUT_C, 96, HID, true, false><<<g32, 256, 0, stream>>>(
        h0b, hq, out_w, out_b,
        nullptr, 0.f, 0.f, out, nullptr);
}